// Round 7
// baseline (439.363 us; speedup 1.0000x reference)
//
#include <hip/hip_runtime.h>

#define NB 8
#define NC 256
#define DF 16384
#define KCL 16
#define SPLITS 16
#define KC (DF / SPLITS)     // 1024
#define BK 32
#define ITERS (KC / BK)      // 32
#define NPAIR 3              // 128x128 upper-tri pairs: (0,0),(0,1),(1,1)
#define GEMM_BLOCKS (NPAIR * 2 * NB * SPLITS)   // 6*8*16 = 768

typedef _Float16 half8 __attribute__((ext_vector_type(8)));
typedef float floatx4 __attribute__((ext_vector_type(4)));

__device__ const int TItab[NPAIR] = {0,0,1};
__device__ const int TJtab[NPAIR] = {0,1,1};

// ---------------- argmax over 256 threads (first occurrence) ---------------------
__device__ __forceinline__ int argmax256(float v, float* sv, int* si) {
  int t = threadIdx.x;
  sv[t] = v; si[t] = t;
  __syncthreads();
  #pragma unroll
  for (int s = 128; s >= 1; s >>= 1) {
    if (t < s) {
      float a = sv[t], b = sv[t + s];
      int ia = si[t], ib = si[t + s];
      if (b > a || (b == a && ib < ia)) { sv[t] = b; si[t] = ib; }
    }
    __syncthreads();
  }
  int r = si[0];
  __syncthreads();
  return r;
}

// ---------------- argmax over 512 threads (first occurrence) ---------------------
__device__ __forceinline__ int argmax512p(float v, float* sv, int* si) {
  int t = threadIdx.x;
  sv[t] = v; si[t] = t;
  __syncthreads();
  #pragma unroll
  for (int s = 256; s >= 1; s >>= 1) {
    if (t < s) {
      float a = sv[t], b = sv[t + s];
      int ia = si[t], ib = si[t + s];
      if (b > a || (b == a && ib < ia)) { sv[t] = b; si[t] = ib; }
    }
    __syncthreads();
  }
  int r = si[0];
  __syncthreads();
  return r;
}

__device__ __forceinline__ void cvt8(const float4 v0, const float4 v1,
                                     half8& h, half8& l) {
  float f[8] = {v0.x, v0.y, v0.z, v0.w, v1.x, v1.y, v1.z, v1.w};
  #pragma unroll
  for (int e = 0; e < 8; ++e) {
    _Float16 hh = (_Float16)f[e];
    h[e] = hh;
    l[e] = (_Float16)(f[e] - (float)hh);
  }
}

// ---------------- K1: fused [barrier-free gemm | pos-FPS block 768] --------------
// Each wave loads its own MFMA fragments from global (no LDS, no __syncthreads),
// converts f32 -> f16 hi/lo in registers, accumulates S = Fh*Fh^T+Fh*Fl^T+Fl*Fh^T
// into ONE chained accumulator, atomically adds into the per-batch Gram G.
__global__ __launch_bounds__(512, 4) void k_gemm_pre(const float* __restrict__ ff,
                                                     const float* __restrict__ pe,
                                                     float* __restrict__ G,
                                                     float* __restrict__ centers0) {
  __shared__ float sm[2064];   // pos-FPS scratch only (gemm blocks never touch LDS)

  const int bid = blockIdx.x;
  const int tid = threadIdx.x;

  if (bid == GEMM_BLOCKS) {
    // ---- pos-FPS (512 threads) ----
    float* px = sm;        float* py = sm + 256;
    float* pz = sm + 512;  float* pn = sm + 768;
    float* sv = sm + 1024; int*   si = (int*)(sm + 1536);  // 512 each
    __shared__ int fpsIdx[KCL];
    const int t = tid;
    const bool valid = t < NC;
    float x = 0.f, y = 0.f, z = 0.f, n = 0.f;
    if (valid) {
      x = pe[t * 3 + 0]; y = pe[t * 3 + 1]; z = pe[t * 3 + 2];
      n = x * x + y * y + z * z;
      px[t] = x; py[t] = y; pz[t] = z; pn[t] = n;
    }
    __syncthreads();
    float rsum = -3.4e38f;
    if (valid) {
      rsum = 0.f;
      for (int j = 0; j < NC; ++j) {
        float dot = x * px[j] + y * py[j] + z * pz[j];
        rsum += sqrtf(fmaxf(n + pn[j] - 2.f * dot, 0.f));
      }
    }
    int start = argmax512p(rsum, sv, si);
    if (t == 0) fpsIdx[0] = start;
    float mind = -3.4e38f;
    if (valid) {
      float dot0 = x * px[start] + y * py[start] + z * pz[start];
      mind = sqrtf(fmaxf(n + pn[start] - 2.f * dot0, 0.f));
    }
    for (int it = 1; it < KCL; ++it) {
      int far = argmax512p(mind, sv, si);
      if (t == 0) fpsIdx[it] = far;
      if (valid) {
        float dot = x * px[far] + y * py[far] + z * pz[far];
        mind = fminf(mind, sqrtf(fmaxf(n + pn[far] - 2.f * dot, 0.f)));
      }
    }
    __syncthreads();
    if (t < KCL) {
      int p = fpsIdx[t];
      centers0[t * 3 + 0] = px[p];
      centers0[t * 3 + 1] = py[p];
      centers0[t * 3 + 2] = pz[p];
    }
    return;
  }

  // ---- gemm block: 128x64 col-half tile of an upper-tri 128x128 pair ----
  const int tc = bid % 6;
  const int b  = (bid / 6) & 7;
  const int sp = bid / 48;
  const int pair = tc >> 1, ch = tc & 1;
  const int ti = TItab[pair], tj = TJtab[pair];
  const bool diag = (ti == tj);

  const int wave = tid >> 6, lane = tid & 63;
  const int wr = wave >> 1, wc = wave & 1;    // 8 waves: 4 row-strips x 2 col-strips
  const int lrow = lane & 15, q = lane >> 4;

  const float* base = ff + (size_t)b * NC * DF + sp * KC + q * 8;
  const float* pA0 = base + (size_t)(ti * 128 + wr * 32 +  0 + lrow) * DF;
  const float* pA1 = base + (size_t)(ti * 128 + wr * 32 + 16 + lrow) * DF;
  const float* pB0 = base + (size_t)(tj * 128 + ch * 64 + wc * 32 +  0 + lrow) * DF;
  const float* pB1 = base + (size_t)(tj * 128 + ch * 64 + wc * 32 + 16 + lrow) * DF;

  floatx4 acc[2][2];
  #pragma unroll
  for (int i = 0; i < 2; ++i)
    #pragma unroll
    for (int j = 0; j < 2; ++j) acc[i][j] = (floatx4)0.f;

  // prefetch iter 0
  float4 va00 = *(const float4*)(pA0), va01 = *(const float4*)(pA0 + 4);
  float4 va10 = *(const float4*)(pA1), va11 = *(const float4*)(pA1 + 4);
  float4 vb00 = *(const float4*)(pB0), vb01 = *(const float4*)(pB0 + 4);
  float4 vb10 = *(const float4*)(pB1), vb11 = *(const float4*)(pB1 + 4);
  pA0 += BK; pA1 += BK; pB0 += BK; pB1 += BK;

  for (int it = 0; it < ITERS; ++it) {
    half8 af[2], lf[2], bh[2], bl[2];
    cvt8(va00, va01, af[0], lf[0]);
    cvt8(va10, va11, af[1], lf[1]);
    cvt8(vb00, vb01, bh[0], bl[0]);
    cvt8(vb10, vb11, bh[1], bl[1]);
    if (it + 1 < ITERS) {   // issue next loads; they fly under the MFMAs below
      va00 = *(const float4*)(pA0); va01 = *(const float4*)(pA0 + 4);
      va10 = *(const float4*)(pA1); va11 = *(const float4*)(pA1 + 4);
      vb00 = *(const float4*)(pB0); vb01 = *(const float4*)(pB0 + 4);
      vb10 = *(const float4*)(pB1); vb11 = *(const float4*)(pB1 + 4);
      pA0 += BK; pA1 += BK; pB0 += BK; pB1 += BK;
    }
    #pragma unroll
    for (int i = 0; i < 2; ++i)
      #pragma unroll
      for (int j = 0; j < 2; ++j) {
        acc[i][j] = __builtin_amdgcn_mfma_f32_16x16x32_f16(af[i], bh[j], acc[i][j], 0, 0, 0);
        acc[i][j] = __builtin_amdgcn_mfma_f32_16x16x32_f16(af[i], bl[j], acc[i][j], 0, 0, 0);
        acc[i][j] = __builtin_amdgcn_mfma_f32_16x16x32_f16(lf[i], bh[j], acc[i][j], 0, 0, 0);
      }
  }

  // epilogue: atomic accumulate into G (splits collide; tiles are disjoint)
  float* Gb = G + (size_t)b * NC * NC;
  #pragma unroll
  for (int i = 0; i < 2; ++i) {
    int grow = ti * 128 + wr * 32 + i * 16 + q * 4;
    #pragma unroll
    for (int j = 0; j < 2; ++j) {
      int gcol = tj * 128 + ch * 64 + wc * 32 + j * 16 + lrow;
      #pragma unroll
      for (int r = 0; r < 4; ++r)
        atomicAdd(&Gb[(size_t)(grow + r) * NC + gcol], acc[i][j][r]);
      if (!diag) {
        #pragma unroll
        for (int r = 0; r < 4; ++r)
          atomicAdd(&Gb[(size_t)gcol * NC + grow + r], acc[i][j][r]);
      }
    }
  }
}

// ---------------- K2: per-batch FPS directly on G (8 blocks) ---------------------
// D rows recomputed on the fly: D(i,t) = sqrt(relu(dg_i + dg_t - 2*G[i][t]))
__global__ __launch_bounds__(256) void k_fps(const float* __restrict__ G,
                                             const float* __restrict__ pe,
                                             float* __restrict__ ccoord) {
  int b = blockIdx.x, t = threadIdx.x;
  const float* Gb = G + (size_t)b * NC * NC;
  __shared__ float dg_s[NC];
  __shared__ float sv[NC]; __shared__ int si[NC];
  __shared__ int fpsIdx[KCL];
  dg_s[t] = Gb[(size_t)t * NC + t];
  __syncthreads();
  float dgt = dg_s[t];
  float rs = 0.f;
  for (int i = 0; i < NC; ++i)
    rs += sqrtf(fmaxf(dg_s[i] + dgt - 2.f * Gb[(size_t)i * NC + t], 0.f));
  int start = argmax256(rs, sv, si);
  if (t == 0) fpsIdx[0] = start;
  float mind = sqrtf(fmaxf(dg_s[start] + dgt - 2.f * Gb[(size_t)start * NC + t], 0.f));
  for (int it = 1; it < KCL; ++it) {
    int far = argmax256(mind, sv, si);
    if (t == 0) fpsIdx[it] = far;
    mind = fminf(mind, sqrtf(fmaxf(dg_s[far] + dgt - 2.f * Gb[(size_t)far * NC + t], 0.f)));
  }
  __syncthreads();
  if (t < KCL) {
    int p = fpsIdx[t];
    ccoord[(b * KCL + t) * 3 + 0] = pe[(b * NC + p) * 3 + 0];
    ccoord[(b * KCL + t) * 3 + 1] = pe[(b * NC + p) * 3 + 1];
    ccoord[(b * KCL + t) * 3 + 2] = pe[(b * NC + p) * 3 + 2];
  }
}

// ---------------- K3: temp_assign + seg-means + matching + update + capacity -----
__global__ __launch_bounds__(256) void k_final(const float* __restrict__ pe,
                                               const float* __restrict__ ccoord,
                                               const float* __restrict__ centers0,
                                               int* __restrict__ outp) {
  __shared__ float cc[NB * KCL * 3];
  __shared__ float cn[NB * KCL];
  __shared__ float sums[KCL][3];
  __shared__ int cnts[KCL];
  __shared__ float avg[KCL][3];
  __shared__ float an[KCL];
  __shared__ float c0[KCL * 3];
  __shared__ float c1x[KCL], c1y[KCL], c1z[KCL], c1n[KCL];
  __shared__ int order[NC][KCL];
  int t = threadIdx.x;
  for (int i = t; i < NB * KCL * 3; i += 256) cc[i] = ccoord[i];
  if (t < KCL * 3) c0[t] = centers0[t];
  if (t < KCL) { sums[t][0] = 0.f; sums[t][1] = 0.f; sums[t][2] = 0.f; cnts[t] = 0; }
  __syncthreads();
  if (t < NB * KCL) {
    float x = cc[t * 3], y = cc[t * 3 + 1], z = cc[t * 3 + 2];
    cn[t] = x * x + y * y + z * z;
  }
  __syncthreads();
  for (int b = 0; b < NB; ++b) {
    int p = b * NC + t;
    float x = pe[p * 3], y = pe[p * 3 + 1], z = pe[p * 3 + 2];
    float n = x * x + y * y + z * z;
    float best = 3.4e38f; int bi = 0;
    #pragma unroll
    for (int k = 0; k < KCL; ++k) {
      int c = b * KCL + k;
      float dot = x * cc[c * 3] + y * cc[c * 3 + 1] + z * cc[c * 3 + 2];
      float d2 = fmaxf(n + cn[c] - 2.f * dot, 0.f);
      if (d2 < best) { best = d2; bi = k; }
    }
    atomicAdd(&sums[bi][0], x);
    atomicAdd(&sums[bi][1], y);
    atomicAdd(&sums[bi][2], z);
    atomicAdd(&cnts[bi], 1);
  }
  __syncthreads();
  if (t < KCL) {
    float c = (float)cnts[t];
    float inv = 1.f / fmaxf(c, 1.f);
    float ax = (cnts[t] > 0) ? sums[t][0] * inv : 0.f;
    float ay = (cnts[t] > 0) ? sums[t][1] * inv : 0.f;
    float az = (cnts[t] > 0) ? sums[t][2] * inv : 0.f;
    avg[t][0] = ax; avg[t][1] = ay; avg[t][2] = az;
    an[t] = ax * ax + ay * ay + az * az;
  }
  __syncthreads();
  if (t < KCL) {
    float x = c0[t * 3], y = c0[t * 3 + 1], z = c0[t * 3 + 2];
    float n = x * x + y * y + z * z;
    float best = 3.4e38f; int bi = 0;
    #pragma unroll
    for (int j = 0; j < KCL; ++j) {
      float dot = x * avg[j][0] + y * avg[j][1] + z * avg[j][2];
      float d2 = fmaxf(n + an[j] - 2.f * dot, 0.f);
      if (d2 < best) { best = d2; bi = j; }
    }
    float nx = 0.8f * x + 0.2f * avg[bi][0];
    float ny = 0.8f * y + 0.2f * avg[bi][1];
    float nz = 0.8f * z + 0.2f * avg[bi][2];
    c1x[t] = nx; c1y[t] = ny; c1z[t] = nz;
    c1n[t] = nx * nx + ny * ny + nz * nz;
  }
  __syncthreads();
  {
    float x = pe[t * 3], y = pe[t * 3 + 1], z = pe[t * 3 + 2];
    float n = x * x + y * y + z * z;
    float v[KCL];
    #pragma unroll
    for (int k = 0; k < KCL; ++k) {
      float dot = x * c1x[k] + y * c1y[k] + z * c1z[k];
      v[k] = fmaxf(n + c1n[k] - 2.f * dot, 0.f);
    }
    bool used[KCL];
    #pragma unroll
    for (int k = 0; k < KCL; ++k) used[k] = false;
    for (int r = 0; r < KCL; ++r) {
      float best = 3.4e38f; int bi = 0;
      #pragma unroll
      for (int j = 0; j < KCL; ++j) {
        if (!used[j] && v[j] < best) { best = v[j]; bi = j; }
      }
      order[t][r] = bi;
      used[bi] = true;
    }
  }
  __syncthreads();
  if (t < 64) {
    int cnt = 0;
    int cur = (t < KCL) ? order[0][t] : 0;
    for (int i = 0; i < NC; ++i) {
      int nxt = (t < KCL && i + 1 < NC) ? order[i + 1][t] : 0;
      int ccur = __shfl(cnt, cur);
      bool avail = (t < KCL) && (ccur < 16);
      unsigned long long m = __ballot(avail);
      int chosen;
      if (m != 0ull) {
        int rank = __ffsll((unsigned long long)m) - 1;
        chosen = __shfl(cur, rank);
      } else {
        chosen = __shfl(cur, 0);
      }
      if (t == chosen) cnt++;
      if (t == 0) outp[i] = chosen;
      cur = nxt;
    }
  }
}

extern "C" void kernel_launch(void* const* d_in, const int* in_sizes, int n_in,
                              void* d_out, int out_size, void* d_ws, size_t ws_size,
                              hipStream_t stream) {
  (void)in_sizes; (void)n_in; (void)out_size; (void)ws_size;
  const float* features = (const float*)d_in[0];
  const float* pe = (const float*)d_in[1];
  char* ws = (char*)d_ws;
  float* G        = (float*)(ws);                  // 8*256*256*4 = 2 MiB
  float* centers0 = (float*)(ws + 2097152);        // 192 B
  float* ccoord   = (float*)(ws + 2097664);        // 1.5 KiB
  int*   outp     = (int*)d_out;

  hipMemsetAsync(G, 0, (size_t)NB * NC * NC * sizeof(float), stream);
  hipLaunchKernelGGL(k_gemm_pre, dim3(GEMM_BLOCKS + 1), dim3(512), 0, stream,
                     features, pe, G, centers0);
  hipLaunchKernelGGL(k_fps, dim3(NB), dim3(256), 0, stream, G, pe, ccoord);
  hipLaunchKernelGGL(k_final, dim3(1), dim3(256), 0, stream, pe, ccoord, centers0, outp);
}